// Round 13
// baseline (824.186 us; speedup 1.0000x reference)
//
#include <hip/hip_runtime.h>
#include <hip/hip_bf16.h>

// ExpertMLPsV2: T=4096, H=2048, I=4096, E=8, TOPK=2.
// Round 13: identical 8-phase schedule/staging as round 12; ONLY change is the
// MFMA shape 16x16x32 -> 32x32x16 (half the instructions, 2x FLOP each) with
// the matching fragment/epilogue layout (C/D: col=lane&31,
// row=(reg&3)+8*(reg>>2)+4*(lane>>5) per m74/m101).

constexpr int kT   = 4096;
constexpr int kH   = 2048;
constexpr int kI   = 4096;
constexpr int kE   = 8;
constexpr int kCap = 4096;
constexpr int kRowsCap = 10240;

typedef __attribute__((ext_vector_type(8))) short bf16x8;
typedef __attribute__((ext_vector_type(4))) float f32x4;
typedef __attribute__((ext_vector_type(16))) float f32x16;

// ---------------- workspace layout ----------------
constexpr size_t HSB_OFF  = 0;                                      // hs bf16 16 MiB
constexpr size_t HBUF_OFF = 16777216;                               // h bf16 rowsCap x kI (80 MiB)
constexpr size_t RA_OFF   = HBUF_OFF + (size_t)kRowsCap * kI * 2;   // wgT -> wdT (128 MiB)
constexpr size_t RB_OFF   = RA_OFF + (size_t)kE * kH * kI * 2;      // wuT -> obuf (128 MiB)
constexpr size_t CNT_OFF  = RB_OFF + (size_t)kE * kH * kI * 2;
constexpr size_t OFF_OFF  = CNT_OFF + 256;
constexpr size_t LTOK_OFF = OFF_OFF + 256;
constexpr size_t LW_OFF   = LTOK_OFF + (size_t)kE * kCap * 4;
constexpr size_t POS_OFF  = LW_OFF + (size_t)kE * kCap * 4;
constexpr size_t WROW_OFF = POS_OFF + (size_t)kT * 2 * 4;
// end ~373 MiB

__device__ __forceinline__ unsigned short f2bf(float x) {   // RNE f32->bf16
  unsigned int u = __float_as_uint(x);
  u += 0x7FFFu + ((u >> 16) & 1u);
  return (unsigned short)(u >> 16);
}
__device__ __forceinline__ unsigned pk2(float a, float b) {
  return (unsigned)f2bf(a) | ((unsigned)f2bf(b) << 16);
}
__device__ __forceinline__ float silu_f(float x) { return x / (1.f + __expf(-x)); }

__device__ __forceinline__ void async_copy16(void* lds, const void* g) {
  __builtin_amdgcn_global_load_lds(
      (const __attribute__((address_space(1))) void*)g,
      (__attribute__((address_space(3))) void*)lds, 16, 0, 0);
}

#define MFMA32 __builtin_amdgcn_mfma_f32_32x32x16_bf16

// ---------------- kernel 1: fp32 -> bf16 hidden states ----------------
__global__ void cvt_hs_kernel(const float* __restrict__ in, unsigned short* __restrict__ out) {
  size_t i = ((size_t)blockIdx.x * 256 + threadIdx.x) * 8;
  float4 a = *(const float4*)(in + i);
  float4 b = *(const float4*)(in + i + 4);
  uint4 v;
  v.x = pk2(a.x, a.y); v.y = pk2(a.z, a.w);
  v.z = pk2(b.x, b.y); v.w = pk2(b.z, b.w);
  *(uint4*)(out + i) = v;
}

// ---------------- kernel 1b: transpose+convert (K,N) f32 -> (N,K) bf16 -------
__global__ __launch_bounds__(256)
void tcvt_kernel(const float* __restrict__ src, unsigned short* __restrict__ dst,
                 int K, int N) {
  __shared__ __attribute__((aligned(16))) unsigned short s[64][72];
  const size_t mat = (size_t)K * N;
  const float* S = src + (size_t)blockIdx.z * mat;
  unsigned short* D = dst + (size_t)blockIdx.z * mat;
  const int k0 = blockIdx.y * 64, n0 = blockIdx.x * 64;
  const int t  = threadIdx.x;
  const int n4 = (t & 15) * 4;
  const int k4 = (t >> 4) * 4;
  const float* p0 = S + (size_t)(k0 + k4) * N + n0 + n4;
  float4 r0 = *(const float4*)(p0);
  float4 r1 = *(const float4*)(p0 + N);
  float4 r2 = *(const float4*)(p0 + 2 * (size_t)N);
  float4 r3 = *(const float4*)(p0 + 3 * (size_t)N);
  uint2 v;
  v.x = pk2(r0.x, r1.x); v.y = pk2(r2.x, r3.x); *(uint2*)(&s[n4 + 0][k4]) = v;
  v.x = pk2(r0.y, r1.y); v.y = pk2(r2.y, r3.y); *(uint2*)(&s[n4 + 1][k4]) = v;
  v.x = pk2(r0.z, r1.z); v.y = pk2(r2.z, r3.z); *(uint2*)(&s[n4 + 2][k4]) = v;
  v.x = pk2(r0.w, r1.w); v.y = pk2(r2.w, r3.w); *(uint2*)(&s[n4 + 3][k4]) = v;
  __syncthreads();
  const int nn = t >> 3;
  const int kc = (t & 7) * 8;
#pragma unroll
  for (int i = 0; i < 2; ++i) {
    const int n = nn + i * 32;
    uint4 u = *(const uint4*)(&s[n][kc]);
    *(uint4*)(D + (size_t)(n0 + n) * K + k0 + kc) = u;
  }
}

// ---------------- kernel 2: routing ----------------
__global__ void route_kernel(const float* __restrict__ aff, const int* __restrict__ idx,
                             int* counts, int* ltok, float* lw, int* pos) {
  int t = blockIdx.x * 256 + threadIdx.x;
  if (t >= kT) return;
  int e0 = idx[t * 2 + 0];
  int e1 = idx[t * 2 + 1];
  float a0 = aff[t * kE + e0];
  float a1 = aff[t * kE + e1];
  if (e0 == e1) {
    float w = a0 / fmaxf(fabsf(a0), 1e-12f);
    int s = atomicAdd(&counts[e0], 1);
    ltok[e0 * kCap + s] = t;
    lw[e0 * kCap + s]   = w;
    pos[t * 2 + 0] = (e0 << 12) | s;
    pos[t * 2 + 1] = -1;
  } else {
    float d = fmaxf(fabsf(a0) + fabsf(a1), 1e-12f);
    int s0 = atomicAdd(&counts[e0], 1);
    ltok[e0 * kCap + s0] = t;
    lw[e0 * kCap + s0]   = a0 / d;
    int s1 = atomicAdd(&counts[e1], 1);
    ltok[e1 * kCap + s1] = t;
    lw[e1 * kCap + s1]   = a1 / d;
    pos[t * 2 + 0] = (e0 << 12) | s0;
    pos[t * 2 + 1] = (e1 << 12) | s1;
  }
}

// 256-aligned prefix offsets
__global__ void prefix_kernel(const int* __restrict__ counts, int* offs) {
  if (threadIdx.x == 0 && blockIdx.x == 0) {
    int acc = 0;
    for (int e = 0; e < kE; ++e) { offs[e] = acc; acc += (counts[e] + 255) & ~255; }
  }
}

// per-slot-row affinity weight (0 for align-pad rows)
__global__ void wrow_kernel(const int* __restrict__ counts, const int* __restrict__ offs,
                            const float* __restrict__ lw, float* __restrict__ wrow) {
  int idx = blockIdx.x * 256 + threadIdx.x;
  int e = idx >> 12, s = idx & 4095;
  int cnt = counts[e];
  int al  = (cnt + 255) & ~255;
  if (s < al) wrow[offs[e] + s] = (s < cnt) ? lw[e * kCap + s] : 0.f;
}

// ---------------- kernel 3: fused gate+up GEMM, 8-phase, 32x32x16 ------------
// BM=256, BN=128(x2 mats), BK=64. 8 waves (2 m-groups x 4 n-panels).
// Per-wave rows: h*128 + wm*64 + mf2*32 (h = region half, mf2 = 0,1).
// LDS buffer (64 KiB): A rows r @ r*128 (halves 0/16384), Wg @32768, Wu @49152.
// grid (kI/128, kCap/256, E), 512 threads.
__global__ __launch_bounds__(512, 2)
void gemm_gu_kernel(const unsigned short* __restrict__ hsb,
                    const unsigned short* __restrict__ wgT,   // (E, I, H) bf16
                    const unsigned short* __restrict__ wuT,
                    const int* __restrict__ counts, const int* __restrict__ offs,
                    const int* __restrict__ ltok, const float* __restrict__ wrow,
                    unsigned short* __restrict__ hbuf) {
  constexpr int NT = kH / 64;   // 32 K-tiles
  __shared__ __attribute__((aligned(16))) unsigned short lds[2 * 32768];

  const int e   = blockIdx.z;
  const int cnt = counts[e];
  const int m0  = blockIdx.y * 256;
  if (m0 >= cnt) return;
  const int n0   = blockIdx.x * 128;
  const int tid  = threadIdx.x;
  const int lane = tid & 63;
  const int wv   = tid >> 6;
  const int wm   = wv >> 2;        // m-group (64 rows in each 128-half)
  const int wn   = wv & 3;         // n-panel of 32
  const int baseRow = offs[e] + m0;

  // staging (identical to round 12): physical slot tid&7 holds logical slot
  // (tid&7)^((tid>>3)&7) -- 8-slot involution per 128B row.
  const int skof = ((tid & 7) ^ ((tid >> 3) & 7)) * 8;
  const int r_   = tid >> 3;
  int s0 = m0 + r_;        s0 = s0 < cnt ? s0 : cnt - 1;
  int s1 = m0 + 64 + r_;   s1 = s1 < cnt ? s1 : cnt - 1;
  int s2 = m0 + 128 + r_;  s2 = s2 < cnt ? s2 : cnt - 1;
  int s3 = m0 + 192 + r_;  s3 = s3 < cnt ? s3 : cnt - 1;
  const unsigned short* aP0 = hsb + (size_t)ltok[e * kCap + s0] * kH + skof;
  const unsigned short* aP1 = hsb + (size_t)ltok[e * kCap + s1] * kH + skof;
  const unsigned short* aP2 = hsb + (size_t)ltok[e * kCap + s2] * kH + skof;
  const unsigned short* aP3 = hsb + (size_t)ltok[e * kCap + s3] * kH + skof;
  const unsigned short* wgP0 = wgT + (size_t)e * kI * kH + (size_t)(n0 + r_) * kH + skof;
  const unsigned short* wgP1 = wgT + (size_t)e * kI * kH + (size_t)(n0 + 64 + r_) * kH + skof;
  const unsigned short* wuP0 = wuT + (size_t)e * kI * kH + (size_t)(n0 + r_) * kH + skof;
  const unsigned short* wuP1 = wuT + (size_t)e * kI * kH + (size_t)(n0 + 64 + r_) * kH + skof;

  char* ldsb = (char*)lds;
  const int stO0 = tid * 16;
  const int stO1 = tid * 16 + 8192;
  const int l31 = lane & 31;
  const int lh  = lane >> 5;
  const int sx  = lane & 7;     // = row&7 for all frag rows (32-aligned bases)

  f32x16 accG[4] = {};          // [h*2 + mf2]
  f32x16 accU[4] = {};
  bf16x8 fA[2][4], fG[4], fU[4];   // fA[mf2][ks], fG/fU[ks]

  const int aoffW = wm * 64 * 128;                 // wave's m-group byte offset
  const int woff  = (wn * 32 + l31) * 128;

#define STG2(dst, p0, p1, tt) {                                   \
    async_copy16((dst) + stO0, (p0) + (size_t)(tt) * 64);         \
    async_copy16((dst) + stO1, (p1) + (size_t)(tt) * 64); }
  // A frags of half h: row = h*128 + wm*64 + mf2*32 + l31; slot = ks*2+lh ^ sx
#define RDA(bc, H) _Pragma("unroll")                                           \
  for (int mf2 = 0; mf2 < 2; ++mf2) {                                          \
    const char* rp_ = (bc) + (H) * 16384 + aoffW + (mf2 * 32 + l31) * 128;     \
    _Pragma("unroll") for (int ks = 0; ks < 4; ++ks)                           \
      fA[mf2][ks] = *(const bf16x8*)(rp_ + (((ks * 2 + lh) ^ sx) << 4));       \
  }
#define RDW(dst, base) _Pragma("unroll")                                       \
  for (int ks = 0; ks < 4; ++ks)                                               \
    dst[ks] = *(const bf16x8*)((base) + woff + (((ks * 2 + lh) ^ sx) << 4));
#define MMA8(ACC, W, H)                                                        \
  __builtin_amdgcn_s_setprio(1);                                               \
  _Pragma("unroll") for (int mf2 = 0; mf2 < 2; ++mf2)                          \
    _Pragma("unroll") for (int ks = 0; ks < 4; ++ks)                           \
      ACC[(H) * 2 + mf2] = MFMA32(W[ks], fA[mf2][ks], ACC[(H) * 2 + mf2], 0, 0, 0); \
  __builtin_amdgcn_s_setprio(0);

  // Tile t (ledger identical to round 12):
  // ph1: rd A(h0),Wg | stage A1(t+1)->bo ; MMA G h0
  // ph2: rd Wu       | stage A0(t+2)->bc ; MMA U h0
  // ph3: rd A(h1)    | stage Wg(t+2)->bc ; MMA G h1
  // ph4:             | stage Wu(t+2)->bc ; MMA U h1 ; vmcnt ; BAR
#define GU_TILE(t, SA1, SM, VM)                                                \
  {                                                                            \
    char* bc = ldsb + ((t) & 1) * 65536;                                       \
    char* bo = ldsb + (((t) + 1) & 1) * 65536;                                 \
    RDA(bc, 0); RDW(fG, bc + 32768);                                           \
    if (SA1) STG2(bo + 16384, aP2, aP3, (t) + 1);                              \
    __builtin_amdgcn_s_barrier();                                              \
    MMA8(accG, fG, 0);                                                         \
    __builtin_amdgcn_s_barrier();                                              \
    RDW(fU, bc + 49152);                                                       \
    if (SM) STG2(bc, aP0, aP1, (t) + 2);                                       \
    __builtin_amdgcn_s_barrier();                                              \
    MMA8(accU, fU, 0);                                                         \
    __builtin_amdgcn_s_barrier();                                              \
    RDA(bc, 1);                                                                \
    if (SM) STG2(bc + 32768, wgP0, wgP1, (t) + 2);                             \
    __builtin_amdgcn_s_barrier();                                              \
    MMA8(accG, fG, 1);                                                         \
    __builtin_amdgcn_s_barrier();                                              \
    if (SM) STG2(bc + 49152, wuP0, wuP1, (t) + 2);                             \
    __builtin_amdgcn_s_barrier();                                              \
    MMA8(accU, fU, 1);                                                         \
    if ((VM) >= 0) {                                                           \
      asm volatile("s_waitcnt vmcnt(%0)" :: "i"((VM) < 0 ? 0 : (VM)) : "memory"); \
      __builtin_amdgcn_s_barrier();                                            \
    }                                                                          \
  }

  // prologue: tile0 complete + tile1's A0/Wg/Wu (A1(1) staged at t0.ph1)
  {
    char* b0 = ldsb;
    char* b1 = ldsb + 65536;
    STG2(b0,         aP0, aP1, 0);
    STG2(b0 + 16384, aP2, aP3, 0);
    STG2(b0 + 32768, wgP0, wgP1, 0);
    STG2(b0 + 49152, wuP0, wuP1, 0);
    STG2(b1,         aP0, aP1, 1);
    STG2(b1 + 32768, wgP0, wgP1, 1);
    STG2(b1 + 49152, wuP0, wuP1, 1);
    asm volatile("s_waitcnt vmcnt(6)" ::: "memory");
    __builtin_amdgcn_s_barrier();
  }

  for (int t = 0; t < NT - 2; ++t) GU_TILE(t, 1, 1, 6);
  GU_TILE(NT - 2, 1, 0, 0);
  GU_TILE(NT - 1, 0, 0, -1);
#undef GU_TILE

  // epilogue: h = silu(g)*u*wrow -> bf16 hbuf.
  // 32x32 C/D: col(lane&31)=m-slot, row reg r: n-offset = (r&3)+8*(r>>2)+4*lh.
#pragma unroll
  for (int hh = 0; hh < 2; ++hh)
#pragma unroll
    for (int mf2 = 0; mf2 < 2; ++mf2) {
      const int a = hh * 2 + mf2;
      const int mrow = baseRow + hh * 128 + wm * 64 + mf2 * 32 + l31;
      const float wf = wrow[mrow];
#pragma unroll
      for (int q = 0; q < 4; ++q) {
        const int n = n0 + wn * 32 + q * 8 + lh * 4;
        float h0 = silu_f(accG[a][q * 4 + 0]) * accU[a][q * 4 + 0] * wf;
        float h1 = silu_f(accG[a][q * 4 + 1]) * accU[a][q * 4 + 1] * wf;
        float h2 = silu_f(accG[a][q * 4 + 2]) * accU[a][q * 4 + 2] * wf;
        float h3 = silu_f(accG[a][q * 4 + 3]) * accU[a][q * 4 + 3] * wf;
        uint2 v;
        v.x = pk2(h0, h1);
        v.y = pk2(h2, h3);
        *(uint2*)(hbuf + ((size_t)mrow * kI + n)) = v;
      }
    }
#undef STG2
#undef RDA
#undef RDW
#undef MMA8
}

// ---------------- kernel 4: down GEMM, 8-phase, 32x32x16 ----------------
// BM=256, BN=256, BK=64. 8 waves; per-wave (2h x 2mf2 x 32m) x (2nh x 32n).
// LDS buffer (64 KiB): A rows @ r*128 (0..32767), W rows @ 32768 + r*128.
// grid (kH/256, kCap/256, E), 512 threads.
__global__ __launch_bounds__(512, 2)
void gemm_dn_kernel(const unsigned short* __restrict__ hbuf,
                    const unsigned short* __restrict__ wdT,   // (E, H, I) bf16
                    const int* __restrict__ counts, const int* __restrict__ offs,
                    float* __restrict__ obuf) {
  constexpr int NT = kI / 64;   // 64 K-tiles
  __shared__ __attribute__((aligned(16))) unsigned short lds[2 * 32768];

  const int e   = blockIdx.z;
  const int cnt = counts[e];
  const int m0  = blockIdx.y * 256;
  if (m0 >= cnt) return;
  const int n0   = blockIdx.x * 256;
  const int tid  = threadIdx.x;
  const int lane = tid & 63;
  const int wv   = tid >> 6;
  const int wm   = wv >> 2;
  const int wn   = wv & 3;
  const int baseRow = offs[e] + m0;

  const int skof = ((tid & 7) ^ ((tid >> 3) & 7)) * 8;
  const int r_   = tid >> 3;
  const unsigned short* aP0 = hbuf + (size_t)(baseRow + r_) * kI + skof;
  const unsigned short* aP1 = hbuf + (size_t)(baseRow + 64 + r_) * kI + skof;
  const unsigned short* aP2 = hbuf + (size_t)(baseRow + 128 + r_) * kI + skof;
  const unsigned short* aP3 = hbuf + (size_t)(baseRow + 192 + r_) * kI + skof;
  const unsigned short* wB = wdT + (size_t)e * kH * kI;
  const unsigned short* wP0 = wB + (size_t)(n0 + r_) * kI + skof;
  const unsigned short* wP1 = wB + (size_t)(n0 + 64 + r_) * kI + skof;
  const unsigned short* wP2 = wB + (size_t)(n0 + 128 + r_) * kI + skof;
  const unsigned short* wP3 = wB + (size_t)(n0 + 192 + r_) * kI + skof;

  char* ldsb = (char*)lds;
  const int stO0 = tid * 16;
  const int stO1 = tid * 16 + 8192;
  const int l31 = lane & 31;
  const int lh  = lane >> 5;
  const int sx  = lane & 7;

  f32x16 acc[4][2] = {};        // [h*2+mf2][nh]
  bf16x8 fA[2][4], w0[4], w1[4];

  const int aoffW = wm * 64 * 128;

#define STG2(dst, p0, p1, tt) {                                   \
    async_copy16((dst) + stO0, (p0) + (size_t)(tt) * 64);         \
    async_copy16((dst) + stO1, (p1) + (size_t)(tt) * 64); }
#define RDA(bc, H) _Pragma("unroll")                                           \
  for (int mf2 = 0; mf2 < 2; ++mf2) {                                          \
    const char* rp_ = (bc) + (H) * 16384 + aoffW + (mf2 * 32 + l31) * 128;     \
    _Pragma("unroll") for (int ks = 0; ks < 4; ++ks)                           \
      fA[mf2][ks] = *(const bf16x8*)(rp_ + (((ks * 2 + lh) ^ sx) << 4));       \
  }
#define RDW(dst, bc, NH) {                                                     \
    const char* rp_ = (bc) + 32768 + ((NH) * 128 + wn * 32 + l31) * 128;       \
    _Pragma("unroll") for (int ks = 0; ks < 4; ++ks)                           \
      dst[ks] = *(const bf16x8*)(rp_ + (((ks * 2 + lh) ^ sx) << 4));           \
  }
#define MMA8(W, H, NH)                                                         \
  __builtin_amdgcn_s_setprio(1);                                               \
  _Pragma("unroll") for (int mf2 = 0; mf2 < 2; ++mf2)                          \
    _Pragma("unroll") for (int ks = 0; ks < 4; ++ks)                           \
      acc[(H) * 2 + mf2][NH] = MFMA32(W[ks], fA[mf2][ks], acc[(H) * 2 + mf2][NH], 0, 0, 0); \
  __builtin_amdgcn_s_setprio(0);

#define DN_TILE(t, SA1, SM, VM)                                                \
  {                                                                            \
    char* bc = ldsb + ((t) & 1) * 65536;                                       \
    char* bo = ldsb + (((t) + 1) & 1) * 65536;                                 \
    RDA(bc, 0); RDW(w0, bc, 0);                                                \
    if (SA1) STG2(bo + 16384, aP2, aP3, (t) + 1);                              \
    __builtin_amdgcn_s_barrier();                                              \
    MMA8(w0, 0, 0);                                                            \
    __builtin_amdgcn_s_barrier();                                              \
    RDW(w1, bc, 1);                                                            \
    if (SM) STG2(bc, aP0, aP1, (t) + 2);                                       \
    __builtin_amdgcn_s_barrier();                                              \
    MMA8(w1, 0, 1);                                                            \
    __builtin_amdgcn_s_barrier();                                              \
    RDA(bc, 1);                                                                \
    if (SM) STG2(bc + 32768, wP0, wP1, (t) + 2);                               \
    __builtin_amdgcn_s_barrier();                                              \
    MMA8(w0, 1, 0);                                                            \
    __builtin_amdgcn_s_barrier();                                              \
    if (SM) STG2(bc + 49152, wP2, wP3, (t) + 2);                               \
    __builtin_amdgcn_s_barrier();                                              \
    MMA8(w1, 1, 1);                                                            \
    if ((VM) >= 0) {                                                           \
      asm volatile("s_waitcnt vmcnt(%0)" :: "i"((VM) < 0 ? 0 : (VM)) : "memory"); \
      __builtin_amdgcn_s_barrier();                                            \
    }                                                                          \
  }

  {
    char* b0 = ldsb;
    char* b1 = ldsb + 65536;
    STG2(b0,         aP0, aP1, 0);
    STG2(b0 + 16384, aP2, aP3, 0);
    STG2(b0 + 32768, wP0, wP1, 0);
    STG2(b0 + 49152, wP2, wP3, 0);
    STG2(b1,         aP0, aP1, 1);
    STG2(b1 + 32768, wP0, wP1, 1);
    STG2(b1 + 49152, wP2, wP3, 1);
    asm volatile("s_waitcnt vmcnt(6)" ::: "memory");
    __builtin_amdgcn_s_barrier();
  }

  for (int t = 0; t < NT - 2; ++t) DN_TILE(t, 1, 1, 6);
  DN_TILE(NT - 2, 1, 0, 0);
  DN_TILE(NT - 1, 0, 0, -1);
#undef DN_TILE

  // epilogue: fp32 stores, reg-quads = 4 consecutive n -> float4
#pragma unroll
  for (int hh = 0; hh < 2; ++hh)
#pragma unroll
    for (int mf2 = 0; mf2 < 2; ++mf2) {
      const int a = hh * 2 + mf2;
      const int mrow = baseRow + hh * 128 + wm * 64 + mf2 * 32 + l31;
#pragma unroll
      for (int nh = 0; nh < 2; ++nh)
#pragma unroll
        for (int q = 0; q < 4; ++q) {
          const int n = n0 + nh * 128 + wn * 32 + q * 8 + lh * 4;
          f32x4 v;
          v[0] = acc[a][nh][q * 4 + 0];
          v[1] = acc[a][nh][q * 4 + 1];
          v[2] = acc[a][nh][q * 4 + 2];
          v[3] = acc[a][nh][q * 4 + 3];
          *(f32x4*)(obuf + (size_t)mrow * kH + n) = v;
        }
    }
#undef STG2
#undef RDA
#undef RDW
#undef MMA8
}

// ---------------- kernel 5: combine obuf slots -> out ----------------
__global__ void combine_kernel(const float* __restrict__ obuf,
                               const int* __restrict__ pos,
                               const int* __restrict__ offs,
                               float* __restrict__ out) {
  const int t   = blockIdx.y;
  const int col = blockIdx.x * 1024 + threadIdx.x * 4;
  const int c0  = pos[t * 2 + 0];
  const int c1  = pos[t * 2 + 1];
  const int row0 = offs[c0 >> 12] + (c0 & 4095);
  float4 v = *(const float4*)(obuf + (size_t)row0 * kH + col);
  if (c1 >= 0) {
    const int row1 = offs[c1 >> 12] + (c1 & 4095);
    float4 w = *(const float4*)(obuf + (size_t)row1 * kH + col);
    v.x += w.x; v.y += w.y; v.z += w.z; v.w += w.w;
  }
  *(float4*)(out + (size_t)t * kH + col) = v;
}

// ---------------- launcher ----------------
extern "C" void kernel_launch(void* const* d_in, const int* in_sizes, int n_in,
                              void* d_out, int out_size, void* d_ws, size_t ws_size,
                              hipStream_t stream) {
  const float* hs   = (const float*)d_in[0];
  const float* aff  = (const float*)d_in[1];
  const int*   eidx = (const int*)d_in[2];
  const float* wg   = (const float*)d_in[3];
  const float* wu   = (const float*)d_in[4];
  const float* wd   = (const float*)d_in[5];
  float* out = (float*)d_out;

  char* ws = (char*)d_ws;
  unsigned short* hsb  = (unsigned short*)(ws + HSB_OFF);
  unsigned short* hbuf = (unsigned short*)(ws + HBUF_OFF);
  unsigned short* wgT  = (unsigned short*)(ws + RA_OFF);   // later: wdT
  unsigned short* wdT  = (unsigned short*)(ws + RA_OFF);
  unsigned short* wuT  = (unsigned short*)(ws + RB_OFF);   // later: obuf
  float*          obuf = (float*)(ws + RB_OFF);
  int*            cnts = (int*)(ws + CNT_OFF);
  int*            offs = (int*)(ws + OFF_OFF);
  int*            ltok = (int*)(ws + LTOK_OFF);
  float*          lwgt = (float*)(ws + LW_OFF);
  int*            pos  = (int*)(ws + POS_OFF);
  float*          wrow = (float*)(ws + WROW_OFF);

  hipMemsetAsync(cnts, 0, kE * sizeof(int), stream);

  cvt_hs_kernel<<<(kT * kH) / (256 * 8), 256, 0, stream>>>(hs, hsb);
  route_kernel<<<kT / 256, 256, 0, stream>>>(aff, eidx, cnts, ltok, lwgt, pos);
  prefix_kernel<<<1, 64, 0, stream>>>(cnts, offs);
  wrow_kernel<<<(kE * kCap) / 256, 256, 0, stream>>>(cnts, offs, lwgt, wrow);

  tcvt_kernel<<<dim3(kI / 64, kH / 64, kE), 256, 0, stream>>>(wg, wgT, kH, kI);
  tcvt_kernel<<<dim3(kI / 64, kH / 64, kE), 256, 0, stream>>>(wu, wuT, kH, kI);

  gemm_gu_kernel<<<dim3(kI / 128, kCap / 256, kE), 512, 0, stream>>>(
      hsb, wgT, wuT, cnts, offs, ltok, wrow, hbuf);

  tcvt_kernel<<<dim3(kH / 64, kI / 64, kE), 256, 0, stream>>>(wd, wdT, kI, kH);

  gemm_dn_kernel<<<dim3(kH / 256, kCap / 256, kE), 512, 0, stream>>>(
      hbuf, wdT, cnts, offs, obuf);

  combine_kernel<<<dim3(kH / 1024, kT), 256, 0, stream>>>(obuf, pos, offs, out);
}

// Round 14
// 718.193 us; speedup vs baseline: 1.1476x; 1.1476x over previous
//
#include <hip/hip_runtime.h>
#include <hip/hip_bf16.h>

// ExpertMLPsV2: T=4096, H=2048, I=4096, E=8, TOPK=2.
// Round 14 = round-12 base (16x16 MFMA, 8-phase gu) +
//  (A) wd-tcvt fused into the gu dispatch (grid.x 96; blocks x>=32 transpose wd
//      into a dedicated wdT region) when ws_size permits, else serial fallback;
//  (B) dn GEMM BN=128 (halved blocks -> kills the 2-slot dispatch tail).

constexpr int kT   = 4096;
constexpr int kH   = 2048;
constexpr int kI   = 4096;
constexpr int kE   = 8;
constexpr int kCap = 4096;
constexpr int kRowsCap = 10240;

typedef __attribute__((ext_vector_type(8))) short bf16x8;
typedef __attribute__((ext_vector_type(4))) float f32x4;

// ---------------- workspace layout ----------------
// smalls live between HSB and HBUF so both modes share offsets.
constexpr size_t HSB_OFF  = 0;                                  // hs bf16 16 MiB
constexpr size_t CNT_OFF  = 16777216;
constexpr size_t OFF_OFF  = CNT_OFF + 4096;
constexpr size_t LTOK_OFF = OFF_OFF + 4096;                     // 128 KiB
constexpr size_t LW_OFF   = LTOK_OFF + (size_t)kE * kCap * 4;   // 128 KiB
constexpr size_t POS_OFF  = LW_OFF + (size_t)kE * kCap * 4;     // 32 KiB
constexpr size_t WROW_OFF = POS_OFF + (size_t)kT * 2 * 4;       // 40 KiB
constexpr size_t HBUF_OFF = 17825792;                           // 17 MiB mark; 80 MiB
constexpr size_t RA_OFF   = HBUF_OFF + (size_t)kRowsCap * kI * 2;   // wgT (128 MiB)
constexpr size_t WMAT_B   = (size_t)kE * kH * kI * 2;
constexpr size_t RB_OFF   = RA_OFF + WMAT_B;                    // wuT (128 MiB)
constexpr size_t WD_OFF   = RB_OFF + WMAT_B;                    // wdT (fused mode)
constexpr size_t WS_NEED  = WD_OFF + WMAT_B;                    // ~481 MiB

__device__ __forceinline__ unsigned short f2bf(float x) {   // RNE f32->bf16
  unsigned int u = __float_as_uint(x);
  u += 0x7FFFu + ((u >> 16) & 1u);
  return (unsigned short)(u >> 16);
}
__device__ __forceinline__ unsigned pk2(float a, float b) {
  return (unsigned)f2bf(a) | ((unsigned)f2bf(b) << 16);
}
__device__ __forceinline__ float silu_f(float x) { return x / (1.f + __expf(-x)); }

__device__ __forceinline__ void async_copy16(void* lds, const void* g) {
  __builtin_amdgcn_global_load_lds(
      (const __attribute__((address_space(1))) void*)g,
      (__attribute__((address_space(3))) void*)lds, 16, 0, 0);
}

#define MFMA_BF16 __builtin_amdgcn_mfma_f32_16x16x32_bf16

// ---------------- kernel 1: fp32 -> bf16 hidden states ----------------
__global__ void cvt_hs_kernel(const float* __restrict__ in, unsigned short* __restrict__ out) {
  size_t i = ((size_t)blockIdx.x * 256 + threadIdx.x) * 8;
  float4 a = *(const float4*)(in + i);
  float4 b = *(const float4*)(in + i + 4);
  uint4 v;
  v.x = pk2(a.x, a.y); v.y = pk2(a.z, a.w);
  v.z = pk2(b.x, b.y); v.w = pk2(b.z, b.w);
  *(uint4*)(out + i) = v;
}

// ---------------- kernel 1b: transpose+convert (K,N) f32 -> (N,K) bf16 -------
__global__ __launch_bounds__(256)
void tcvt_kernel(const float* __restrict__ src, unsigned short* __restrict__ dst,
                 int K, int N) {
  __shared__ __attribute__((aligned(16))) unsigned short s[64][72];
  const size_t mat = (size_t)K * N;
  const float* S = src + (size_t)blockIdx.z * mat;
  unsigned short* D = dst + (size_t)blockIdx.z * mat;
  const int k0 = blockIdx.y * 64, n0 = blockIdx.x * 64;
  const int t  = threadIdx.x;
  const int n4 = (t & 15) * 4;
  const int k4 = (t >> 4) * 4;
  const float* p0 = S + (size_t)(k0 + k4) * N + n0 + n4;
  float4 r0 = *(const float4*)(p0);
  float4 r1 = *(const float4*)(p0 + N);
  float4 r2 = *(const float4*)(p0 + 2 * (size_t)N);
  float4 r3 = *(const float4*)(p0 + 3 * (size_t)N);
  uint2 v;
  v.x = pk2(r0.x, r1.x); v.y = pk2(r2.x, r3.x); *(uint2*)(&s[n4 + 0][k4]) = v;
  v.x = pk2(r0.y, r1.y); v.y = pk2(r2.y, r3.y); *(uint2*)(&s[n4 + 1][k4]) = v;
  v.x = pk2(r0.z, r1.z); v.y = pk2(r2.z, r3.z); *(uint2*)(&s[n4 + 2][k4]) = v;
  v.x = pk2(r0.w, r1.w); v.y = pk2(r2.w, r3.w); *(uint2*)(&s[n4 + 3][k4]) = v;
  __syncthreads();
  const int nn = t >> 3;
  const int kc = (t & 7) * 8;
#pragma unroll
  for (int i = 0; i < 2; ++i) {
    const int n = nn + i * 32;
    uint4 u = *(const uint4*)(&s[n][kc]);
    *(uint4*)(D + (size_t)(n0 + n) * K + k0 + kc) = u;
  }
}

// ---------------- kernel 2: routing ----------------
__global__ void route_kernel(const float* __restrict__ aff, const int* __restrict__ idx,
                             int* counts, int* ltok, float* lw, int* pos) {
  int t = blockIdx.x * 256 + threadIdx.x;
  if (t >= kT) return;
  int e0 = idx[t * 2 + 0];
  int e1 = idx[t * 2 + 1];
  float a0 = aff[t * kE + e0];
  float a1 = aff[t * kE + e1];
  if (e0 == e1) {
    float w = a0 / fmaxf(fabsf(a0), 1e-12f);
    int s = atomicAdd(&counts[e0], 1);
    ltok[e0 * kCap + s] = t;
    lw[e0 * kCap + s]   = w;
    pos[t * 2 + 0] = (e0 << 12) | s;
    pos[t * 2 + 1] = -1;
  } else {
    float d = fmaxf(fabsf(a0) + fabsf(a1), 1e-12f);
    int s0 = atomicAdd(&counts[e0], 1);
    ltok[e0 * kCap + s0] = t;
    lw[e0 * kCap + s0]   = a0 / d;
    int s1 = atomicAdd(&counts[e1], 1);
    ltok[e1 * kCap + s1] = t;
    lw[e1 * kCap + s1]   = a1 / d;
    pos[t * 2 + 0] = (e0 << 12) | s0;
    pos[t * 2 + 1] = (e1 << 12) | s1;
  }
}

// 256-aligned prefix offsets
__global__ void prefix_kernel(const int* __restrict__ counts, int* offs) {
  if (threadIdx.x == 0 && blockIdx.x == 0) {
    int acc = 0;
    for (int e = 0; e < kE; ++e) { offs[e] = acc; acc += (counts[e] + 255) & ~255; }
  }
}

// per-slot-row affinity weight (0 for align-pad rows)
__global__ void wrow_kernel(const int* __restrict__ counts, const int* __restrict__ offs,
                            const float* __restrict__ lw, float* __restrict__ wrow) {
  int idx = blockIdx.x * 256 + threadIdx.x;
  int e = idx >> 12, s = idx & 4095;
  int cnt = counts[e];
  int al  = (cnt + 255) & ~255;
  if (s < al) wrow[offs[e] + s] = (s < cnt) ? lw[e * kCap + s] : 0.f;
}

// wd transpose path run by gu-dispatch blocks x>=32 (fused mode).
// 512 threads handle a 64k x 128n region = two 64x64 sub-tiles.
__device__ __forceinline__ void wd_path(const float* __restrict__ wd,
                                        unsigned short* __restrict__ wdT,
                                        int xp, int y, int z, int tid, char* ldsraw) {
  const int q  = xp + 64 * y;            // [0, 1024)
  const int kt = q & 63, np = q >> 6;
  const int K = kI, N = kH;
  const float* S = wd + (size_t)z * K * N;
  unsigned short* D = wdT + (size_t)z * K * N;
  const int sub = tid >> 8, t = tid & 255;
  const int k0 = kt * 64, n0 = np * 128 + sub * 64;
  unsigned short (*s)[72] = (unsigned short(*)[72])(ldsraw + sub * 9216);
  const int n4 = (t & 15) * 4;
  const int k4 = (t >> 4) * 4;
  const float* p0 = S + (size_t)(k0 + k4) * N + n0 + n4;
  float4 r0 = *(const float4*)(p0);
  float4 r1 = *(const float4*)(p0 + N);
  float4 r2 = *(const float4*)(p0 + 2 * (size_t)N);
  float4 r3 = *(const float4*)(p0 + 3 * (size_t)N);
  uint2 v;
  v.x = pk2(r0.x, r1.x); v.y = pk2(r2.x, r3.x); *(uint2*)(&s[n4 + 0][k4]) = v;
  v.x = pk2(r0.y, r1.y); v.y = pk2(r2.y, r3.y); *(uint2*)(&s[n4 + 1][k4]) = v;
  v.x = pk2(r0.z, r1.z); v.y = pk2(r2.z, r3.z); *(uint2*)(&s[n4 + 2][k4]) = v;
  v.x = pk2(r0.w, r1.w); v.y = pk2(r2.w, r3.w); *(uint2*)(&s[n4 + 3][k4]) = v;
  __syncthreads();
  const int nn = t >> 3;
  const int kc = (t & 7) * 8;
#pragma unroll
  for (int i = 0; i < 2; ++i) {
    const int n = nn + i * 32;
    uint4 u = *(const uint4*)(&s[n][kc]);
    *(uint4*)(D + (size_t)(n0 + n) * K + k0 + kc) = u;
  }
}

// ---------------- kernel 3: fused gate+up GEMM, 8-phase (round-12) -----------
// + fused wd-tcvt side path for blockIdx.x >= 32.
__global__ __launch_bounds__(512, 2)
void gemm_gu_kernel(const unsigned short* __restrict__ hsb,
                    const unsigned short* __restrict__ wgT,   // (E, I, H) bf16
                    const unsigned short* __restrict__ wuT,
                    const int* __restrict__ counts, const int* __restrict__ offs,
                    const int* __restrict__ ltok, const float* __restrict__ wrow,
                    unsigned short* __restrict__ hbuf,
                    const float* __restrict__ wdSrc,          // fused mode only
                    unsigned short* __restrict__ wdDst) {
  constexpr int NT = kH / 64;   // 32 K-tiles
  __shared__ __attribute__((aligned(16))) unsigned short lds[2 * 32768];

  if (blockIdx.x >= 32) {   // wd transpose blocks (fused mode)
    wd_path(wdSrc, wdDst, blockIdx.x - 32, blockIdx.y, blockIdx.z,
            threadIdx.x, (char*)lds);
    return;
  }

  const int e   = blockIdx.z;
  const int cnt = counts[e];
  const int m0  = blockIdx.y * 256;
  if (m0 >= cnt) return;
  const int n0   = blockIdx.x * 128;
  const int tid  = threadIdx.x;
  const int lane = tid & 63;
  const int wv   = tid >> 6;
  const int wm   = wv >> 2;        // m-group (64 rows in each 128-half)
  const int wn   = wv & 3;         // n-panel of 32
  const int baseRow = offs[e] + m0;

  const int skof = ((tid & 7) ^ ((tid >> 3) & 7)) * 8;
  const int r_   = tid >> 3;
  int s0 = m0 + r_;        s0 = s0 < cnt ? s0 : cnt - 1;
  int s1 = m0 + 64 + r_;   s1 = s1 < cnt ? s1 : cnt - 1;
  int s2 = m0 + 128 + r_;  s2 = s2 < cnt ? s2 : cnt - 1;
  int s3 = m0 + 192 + r_;  s3 = s3 < cnt ? s3 : cnt - 1;
  const unsigned short* aP0 = hsb + (size_t)ltok[e * kCap + s0] * kH + skof;
  const unsigned short* aP1 = hsb + (size_t)ltok[e * kCap + s1] * kH + skof;
  const unsigned short* aP2 = hsb + (size_t)ltok[e * kCap + s2] * kH + skof;
  const unsigned short* aP3 = hsb + (size_t)ltok[e * kCap + s3] * kH + skof;
  const unsigned short* wgP0 = wgT + (size_t)e * kI * kH + (size_t)(n0 + r_) * kH + skof;
  const unsigned short* wgP1 = wgT + (size_t)e * kI * kH + (size_t)(n0 + 64 + r_) * kH + skof;
  const unsigned short* wuP0 = wuT + (size_t)e * kI * kH + (size_t)(n0 + r_) * kH + skof;
  const unsigned short* wuP1 = wuT + (size_t)e * kI * kH + (size_t)(n0 + 64 + r_) * kH + skof;

  char* ldsb = (char*)lds;
  const int stO0 = tid * 16;
  const int stO1 = tid * 16 + 8192;
  const int ar  = lane & 15;
  const int lg  = lane >> 4;
  const int sk0 = ((lg ^ (lane & 7)) << 4);
  const int sk1 = (((4 + lg) ^ (lane & 7)) << 4);

  f32x4 accG[8][2] = {};
  f32x4 accU[8][2] = {};
  bf16x8 a0[4][2], a1[4][2], wgf[2][2], wuf[2][2];

#define STG2(dst, p0, p1, tt) {                                   \
    async_copy16((dst) + stO0, (p0) + (size_t)(tt) * 64);         \
    async_copy16((dst) + stO1, (p1) + (size_t)(tt) * 64); }
#define RD_A(dst, base, mh) _Pragma("unroll")                                  \
  for (int mf = 0; mf < 4; ++mf) {                                             \
    const char* rp_ = (base) + ((mh) * 128 + wm * 64 + mf * 16 + ar) * 128;    \
    dst[mf][0] = *(const bf16x8*)(rp_ + sk0);                                  \
    dst[mf][1] = *(const bf16x8*)(rp_ + sk1); }
#define RD_W(dst, base) _Pragma("unroll")                                      \
  for (int nf = 0; nf < 2; ++nf) {                                             \
    const char* rp_ = (base) + (wn * 32 + nf * 16 + ar) * 128;                 \
    dst[nf][0] = *(const bf16x8*)(rp_ + sk0);                                  \
    dst[nf][1] = *(const bf16x8*)(rp_ + sk1); }
#define MMA16(ACC, W, A, MH)                                                   \
  __builtin_amdgcn_s_setprio(1);                                               \
  _Pragma("unroll") for (int mf = 0; mf < 4; ++mf)                             \
    _Pragma("unroll") for (int nf = 0; nf < 2; ++nf) {                         \
      ACC[(MH)*4+mf][nf] = MFMA_BF16(W[nf][0], A[mf][0], ACC[(MH)*4+mf][nf], 0, 0, 0); \
      ACC[(MH)*4+mf][nf] = MFMA_BF16(W[nf][1], A[mf][1], ACC[(MH)*4+mf][nf], 0, 0, 0); \
    }                                                                          \
  __builtin_amdgcn_s_setprio(0);

#define GU_TILE(t, SA1, SM, VM)                                                \
  {                                                                            \
    char* bc = ldsb + ((t) & 1) * 65536;                                       \
    char* bo = ldsb + (((t) + 1) & 1) * 65536;                                 \
    RD_A(a0, bc, 0); RD_W(wgf, bc + 32768);                                    \
    if (SA1) STG2(bo + 16384, aP2, aP3, (t) + 1);                              \
    __builtin_amdgcn_s_barrier();                                              \
    MMA16(accG, wgf, a0, 0);                                                   \
    __builtin_amdgcn_s_barrier();                                              \
    RD_W(wuf, bc + 49152);                                                     \
    if (SM) STG2(bc, aP0, aP1, (t) + 2);                                       \
    __builtin_amdgcn_s_barrier();                                              \
    MMA16(accU, wuf, a0, 0);                                                   \
    __builtin_amdgcn_s_barrier();                                              \
    RD_A(a1, bc, 1);                                                           \
    if (SM) STG2(bc + 32768, wgP0, wgP1, (t) + 2);                             \
    __builtin_amdgcn_s_barrier();                                              \
    MMA16(accG, wgf, a1, 1);                                                   \
    __builtin_amdgcn_s_barrier();                                              \
    if (SM) STG2(bc + 49152, wuP0, wuP1, (t) + 2);                             \
    __builtin_amdgcn_s_barrier();                                              \
    MMA16(accU, wuf, a1, 1);                                                   \
    if ((VM) >= 0) {                                                           \
      asm volatile("s_waitcnt vmcnt(%0)" :: "i"((VM) < 0 ? 0 : (VM)) : "memory"); \
      __builtin_amdgcn_s_barrier();                                            \
    }                                                                          \
  }

  {
    char* b0 = ldsb;
    char* b1 = ldsb + 65536;
    STG2(b0,         aP0, aP1, 0);
    STG2(b0 + 16384, aP2, aP3, 0);
    STG2(b0 + 32768, wgP0, wgP1, 0);
    STG2(b0 + 49152, wuP0, wuP1, 0);
    STG2(b1,         aP0, aP1, 1);
    STG2(b1 + 32768, wgP0, wgP1, 1);
    STG2(b1 + 49152, wuP0, wuP1, 1);
    asm volatile("s_waitcnt vmcnt(6)" ::: "memory");
    __builtin_amdgcn_s_barrier();
  }

  for (int t = 0; t < NT - 2; ++t) GU_TILE(t, 1, 1, 6);
  GU_TILE(NT - 2, 1, 0, 0);
  GU_TILE(NT - 1, 0, 0, -1);
#undef GU_TILE

  const int lr4 = lg * 4;
#pragma unroll
  for (int mh = 0; mh < 2; ++mh)
#pragma unroll
    for (int mf = 0; mf < 4; ++mf) {
      const int grow = baseRow + mh * 128 + wm * 64 + mf * 16 + ar;
      const float wf = wrow[grow];
#pragma unroll
      for (int nf = 0; nf < 2; ++nf) {
        const int n = n0 + wn * 32 + nf * 16 + lr4;
        f32x4 g = accG[mh * 4 + mf][nf], u = accU[mh * 4 + mf][nf];
        float h0 = silu_f(g[0]) * u[0] * wf;
        float h1 = silu_f(g[1]) * u[1] * wf;
        float h2 = silu_f(g[2]) * u[2] * wf;
        float h3 = silu_f(g[3]) * u[3] * wf;
        uint2 v;
        v.x = pk2(h0, h1);
        v.y = pk2(h2, h3);
        *(uint2*)(hbuf + ((size_t)grow * kI + n)) = v;
      }
    }
#undef STG2
#undef RD_A
#undef RD_W
#undef MMA16
}

// ---------------- kernel 4: down GEMM, BM=256, BN=128, 2-phase ---------------
// 8 waves (2m x 4n): per-wave 128m x 32n -> acc[8][2] (64 regs).
// LDS per buffer (48 KiB): A [256][64] @0 (halves 0/16384), W [128][64] @32768.
// Stages/tile: A0, A1, W (6 instr); vmcnt(4) at tile end.
// grid (kH/128=16, kCap/256, E), 512 threads.
__global__ __launch_bounds__(512, 2)
void gemm_dn_kernel(const unsigned short* __restrict__ hbuf,
                    const unsigned short* __restrict__ wdT,   // (E, H, I) bf16
                    const int* __restrict__ counts, const int* __restrict__ offs,
                    float* __restrict__ obuf) {
  constexpr int NT = kI / 64;   // 64 K-tiles
  __shared__ __attribute__((aligned(16))) unsigned short lds[2 * 24576];

  const int e   = blockIdx.z;
  const int cnt = counts[e];
  const int m0  = blockIdx.y * 256;
  if (m0 >= cnt) return;
  const int n0   = blockIdx.x * 128;
  const int tid  = threadIdx.x;
  const int lane = tid & 63;
  const int wv   = tid >> 6;
  const int wm   = wv >> 2;
  const int wn   = wv & 3;
  const int baseRow = offs[e] + m0;

  const int skof = ((tid & 7) ^ ((tid >> 3) & 7)) * 8;
  const int r_   = tid >> 3;
  const unsigned short* aP0 = hbuf + (size_t)(baseRow + r_) * kI + skof;
  const unsigned short* aP1 = hbuf + (size_t)(baseRow + 64 + r_) * kI + skof;
  const unsigned short* aP2 = hbuf + (size_t)(baseRow + 128 + r_) * kI + skof;
  const unsigned short* aP3 = hbuf + (size_t)(baseRow + 192 + r_) * kI + skof;
  const unsigned short* wB = wdT + (size_t)e * kH * kI;
  const unsigned short* wP0 = wB + (size_t)(n0 + r_) * kI + skof;
  const unsigned short* wP1 = wB + (size_t)(n0 + 64 + r_) * kI + skof;

  char* ldsb = (char*)lds;
  const int stO0 = tid * 16;
  const int stO1 = tid * 16 + 8192;
  const int ar  = lane & 15;
  const int lg  = lane >> 4;
  const int sk0 = ((lg ^ (lane & 7)) << 4);
  const int sk1 = (((4 + lg) ^ (lane & 7)) << 4);

  f32x4 acc[8][2] = {};
  bf16x8 a0[4][2], a1[4][2], w0[2][2];

#define STG2(dst, p0, p1, tt) {                                   \
    async_copy16((dst) + stO0, (p0) + (size_t)(tt) * 64);         \
    async_copy16((dst) + stO1, (p1) + (size_t)(tt) * 64); }
#define RD_A(dst, base, mh) _Pragma("unroll")                                  \
  for (int mf = 0; mf < 4; ++mf) {                                             \
    const char* rp_ = (base) + ((mh) * 128 + wm * 64 + mf * 16 + ar) * 128;    \
    dst[mf][0] = *(const bf16x8*)(rp_ + sk0);                                  \
    dst[mf][1] = *(const bf16x8*)(rp_ + sk1); }
#define RD_W(dst, base) _Pragma("unroll")                                      \
  for (int nf = 0; nf < 2; ++nf) {                                             \
    const char* rp_ = (base) + 32768 + (wn * 32 + nf * 16 + ar) * 128;         \
    dst[nf][0] = *(const bf16x8*)(rp_ + sk0);                                  \
    dst[nf][1] = *(const bf16x8*)(rp_ + sk1); }
#define MMA16(A, MH)                                                           \
  __builtin_amdgcn_s_setprio(1);                                               \
  _Pragma("unroll") for (int mf = 0; mf < 4; ++mf)                             \
    _Pragma("unroll") for (int nf = 0; nf < 2; ++nf) {                         \
      acc[(MH)*4+mf][nf] = MFMA_BF16(w0[nf][0], A[mf][0], acc[(MH)*4+mf][nf], 0, 0, 0); \
      acc[(MH)*4+mf][nf] = MFMA_BF16(w0[nf][1], A[mf][1], acc[(MH)*4+mf][nf], 0, 0, 0); \
    }                                                                          \
  __builtin_amdgcn_s_setprio(0);

  // Tile t: ph1 { rdA(h0), rdW | stage A1(t+1)->bo | BAR | MMA h0 | BAR }
  //         ph2 { rdA(h1) | stage A0(t+2),W(t+2)->bc | BAR | MMA h1 | vm | BAR }
#define DN_TILE(t, SA1, SM, VM)                                                \
  {                                                                            \
    char* bc = ldsb + ((t) & 1) * 49152;                                       \
    char* bo = ldsb + (((t) + 1) & 1) * 49152;                                 \
    RD_A(a0, bc, 0); RD_W(w0, bc);                                             \
    if (SA1) STG2(bo + 16384, aP2, aP3, (t) + 1);                              \
    __builtin_amdgcn_s_barrier();                                              \
    MMA16(a0, 0);                                                              \
    __builtin_amdgcn_s_barrier();                                              \
    RD_A(a1, bc, 1);                                                           \
    if (SM) { STG2(bc, aP0, aP1, (t) + 2);                                     \
              STG2(bc + 32768, wP0, wP1, (t) + 2); }                           \
    __builtin_amdgcn_s_barrier();                                              \
    MMA16(a1, 1);                                                              \
    if ((VM) >= 0) {                                                           \
      asm volatile("s_waitcnt vmcnt(%0)" :: "i"((VM) < 0 ? 0 : (VM)) : "memory"); \
      __builtin_amdgcn_s_barrier();                                            \
    }                                                                          \
  }

  {
    char* b0 = ldsb;
    char* b1 = ldsb + 49152;
    STG2(b0,         aP0, aP1, 0);
    STG2(b0 + 16384, aP2, aP3, 0);
    STG2(b0 + 32768, wP0, wP1, 0);
    STG2(b1,         aP0, aP1, 1);
    STG2(b1 + 32768, wP0, wP1, 1);
    asm volatile("s_waitcnt vmcnt(4)" ::: "memory");
    __builtin_amdgcn_s_barrier();
  }

  for (int t = 0; t < NT - 2; ++t) DN_TILE(t, 1, 1, 4);
  DN_TILE(NT - 2, 1, 0, 0);
  DN_TILE(NT - 1, 0, 0, -1);
#undef DN_TILE

  const int lr4 = lg * 4;
#pragma unroll
  for (int mh = 0; mh < 2; ++mh)
#pragma unroll
    for (int mf = 0; mf < 4; ++mf) {
      const int grow = baseRow + mh * 128 + wm * 64 + mf * 16 + ar;
#pragma unroll
      for (int nf = 0; nf < 2; ++nf) {
        const int n = n0 + wn * 32 + nf * 16 + lr4;
        *(f32x4*)(obuf + (size_t)grow * kH + n) = acc[mh * 4 + mf][nf];
      }
    }
#undef STG2
#undef RD_A
#undef RD_W
#undef MMA16
}

// ---------------- kernel 5: combine obuf slots -> out ----------------
__global__ void combine_kernel(const float* __restrict__ obuf,
                               const int* __restrict__ pos,
                               const int* __restrict__ offs,
                               float* __restrict__ out) {
  const int t   = blockIdx.y;
  const int col = blockIdx.x * 1024 + threadIdx.x * 4;
  const int c0  = pos[t * 2 + 0];
  const int c1  = pos[t * 2 + 1];
  const int row0 = offs[c0 >> 12] + (c0 & 4095);
  float4 v = *(const float4*)(obuf + (size_t)row0 * kH + col);
  if (c1 >= 0) {
    const int row1 = offs[c1 >> 12] + (c1 & 4095);
    float4 w = *(const float4*)(obuf + (size_t)row1 * kH + col);
    v.x += w.x; v.y += w.y; v.z += w.z; v.w += w.w;
  }
  *(float4*)(out + (size_t)t * kH + col) = v;
}

// ---------------- launcher ----------------
extern "C" void kernel_launch(void* const* d_in, const int* in_sizes, int n_in,
                              void* d_out, int out_size, void* d_ws, size_t ws_size,
                              hipStream_t stream) {
  const float* hs   = (const float*)d_in[0];
  const float* aff  = (const float*)d_in[1];
  const int*   eidx = (const int*)d_in[2];
  const float* wg   = (const float*)d_in[3];
  const float* wu   = (const float*)d_in[4];
  const float* wd   = (const float*)d_in[5];
  float* out = (float*)d_out;

  char* ws = (char*)d_ws;
  unsigned short* hsb  = (unsigned short*)(ws + HSB_OFF);
  unsigned short* hbuf = (unsigned short*)(ws + HBUF_OFF);
  unsigned short* wgT  = (unsigned short*)(ws + RA_OFF);
  unsigned short* wuT  = (unsigned short*)(ws + RB_OFF);
  int*            cnts = (int*)(ws + CNT_OFF);
  int*            offs = (int*)(ws + OFF_OFF);
  int*            ltok = (int*)(ws + LTOK_OFF);
  float*          lwgt = (float*)(ws + LW_OFF);
  int*            pos  = (int*)(ws + POS_OFF);
  float*          wrow = (float*)(ws + WROW_OFF);

  const bool fused = (ws_size >= WS_NEED);
  unsigned short* wdT  = fused ? (unsigned short*)(ws + WD_OFF)
                               : (unsigned short*)(ws + RA_OFF);   // after gu, wgT dead
  float*          obuf = fused ? (float*)(ws + RA_OFF)             // after gu, wgT dead
                               : (float*)(ws + RB_OFF);            // after gu, wuT dead

  hipMemsetAsync(cnts, 0, kE * sizeof(int), stream);

  cvt_hs_kernel<<<(kT * kH) / (256 * 8), 256, 0, stream>>>(hs, hsb);
  route_kernel<<<kT / 256, 256, 0, stream>>>(aff, eidx, cnts, ltok, lwgt, pos);
  prefix_kernel<<<1, 64, 0, stream>>>(cnts, offs);
  wrow_kernel<<<(kE * kCap) / 256, 256, 0, stream>>>(cnts, offs, lwgt, wrow);

  tcvt_kernel<<<dim3(kI / 64, kH / 64, kE), 256, 0, stream>>>(wg, wgT, kH, kI);
  tcvt_kernel<<<dim3(kI / 64, kH / 64, kE), 256, 0, stream>>>(wu, wuT, kH, kI);

  if (fused) {
    // gu blocks (x<32) + wd-transpose blocks (x in [32,96))
    gemm_gu_kernel<<<dim3(96, kCap / 256, kE), 512, 0, stream>>>(
        hsb, wgT, wuT, cnts, offs, ltok, wrow, hbuf, wd, wdT);
  } else {
    gemm_gu_kernel<<<dim3(32, kCap / 256, kE), 512, 0, stream>>>(
        hsb, wgT, wuT, cnts, offs, ltok, wrow, hbuf, nullptr, nullptr);
    tcvt_kernel<<<dim3(kH / 64, kI / 64, kE), 256, 0, stream>>>(wd, wdT, kI, kH);
  }

  gemm_dn_kernel<<<dim3(kH / 128, kCap / 256, kE), 512, 0, stream>>>(
      hbuf, wdT, cnts, offs, obuf);

  combine_kernel<<<dim3(kH / 1024, kT), 256, 0, stream>>>(obuf, pos, offs, out);
}

// Round 15
// 689.205 us; speedup vs baseline: 1.1959x; 1.0421x over previous
//
#include <hip/hip_runtime.h>
#include <hip/hip_bf16.h>

// ExpertMLPsV2: T=4096, H=2048, I=4096, E=8, TOPK=2.
// Round 15 = round-14 + dn repack: BM=128/BN=128, dbuf 64KB -> 2 blocks/CU,
// launch_bounds(512,4) (4 waves/SIMD), ~1056 small blocks -> ~3% packing waste.
// gu (incl fused wd-tcvt) untouched.

constexpr int kT   = 4096;
constexpr int kH   = 2048;
constexpr int kI   = 4096;
constexpr int kE   = 8;
constexpr int kCap = 4096;
constexpr int kRowsCap = 10240;

typedef __attribute__((ext_vector_type(8))) short bf16x8;
typedef __attribute__((ext_vector_type(4))) float f32x4;

// ---------------- workspace layout ----------------
constexpr size_t HSB_OFF  = 0;                                  // hs bf16 16 MiB
constexpr size_t CNT_OFF  = 16777216;
constexpr size_t OFF_OFF  = CNT_OFF + 4096;
constexpr size_t LTOK_OFF = OFF_OFF + 4096;
constexpr size_t LW_OFF   = LTOK_OFF + (size_t)kE * kCap * 4;
constexpr size_t POS_OFF  = LW_OFF + (size_t)kE * kCap * 4;
constexpr size_t WROW_OFF = POS_OFF + (size_t)kT * 2 * 4;
constexpr size_t HBUF_OFF = 17825792;                           // 80 MiB
constexpr size_t RA_OFF   = HBUF_OFF + (size_t)kRowsCap * kI * 2;   // wgT (128 MiB)
constexpr size_t WMAT_B   = (size_t)kE * kH * kI * 2;
constexpr size_t RB_OFF   = RA_OFF + WMAT_B;                    // wuT (128 MiB)
constexpr size_t WD_OFF   = RB_OFF + WMAT_B;                    // wdT (fused mode)
constexpr size_t WS_NEED  = WD_OFF + WMAT_B;                    // ~481 MiB

__device__ __forceinline__ unsigned short f2bf(float x) {   // RNE f32->bf16
  unsigned int u = __float_as_uint(x);
  u += 0x7FFFu + ((u >> 16) & 1u);
  return (unsigned short)(u >> 16);
}
__device__ __forceinline__ unsigned pk2(float a, float b) {
  return (unsigned)f2bf(a) | ((unsigned)f2bf(b) << 16);
}
__device__ __forceinline__ float silu_f(float x) { return x / (1.f + __expf(-x)); }

__device__ __forceinline__ void async_copy16(void* lds, const void* g) {
  __builtin_amdgcn_global_load_lds(
      (const __attribute__((address_space(1))) void*)g,
      (__attribute__((address_space(3))) void*)lds, 16, 0, 0);
}

#define MFMA_BF16 __builtin_amdgcn_mfma_f32_16x16x32_bf16

// ---------------- kernel 1: fp32 -> bf16 hidden states ----------------
__global__ void cvt_hs_kernel(const float* __restrict__ in, unsigned short* __restrict__ out) {
  size_t i = ((size_t)blockIdx.x * 256 + threadIdx.x) * 8;
  float4 a = *(const float4*)(in + i);
  float4 b = *(const float4*)(in + i + 4);
  uint4 v;
  v.x = pk2(a.x, a.y); v.y = pk2(a.z, a.w);
  v.z = pk2(b.x, b.y); v.w = pk2(b.z, b.w);
  *(uint4*)(out + i) = v;
}

// ---------------- kernel 1b: transpose+convert (K,N) f32 -> (N,K) bf16 -------
__global__ __launch_bounds__(256)
void tcvt_kernel(const float* __restrict__ src, unsigned short* __restrict__ dst,
                 int K, int N) {
  __shared__ __attribute__((aligned(16))) unsigned short s[64][72];
  const size_t mat = (size_t)K * N;
  const float* S = src + (size_t)blockIdx.z * mat;
  unsigned short* D = dst + (size_t)blockIdx.z * mat;
  const int k0 = blockIdx.y * 64, n0 = blockIdx.x * 64;
  const int t  = threadIdx.x;
  const int n4 = (t & 15) * 4;
  const int k4 = (t >> 4) * 4;
  const float* p0 = S + (size_t)(k0 + k4) * N + n0 + n4;
  float4 r0 = *(const float4*)(p0);
  float4 r1 = *(const float4*)(p0 + N);
  float4 r2 = *(const float4*)(p0 + 2 * (size_t)N);
  float4 r3 = *(const float4*)(p0 + 3 * (size_t)N);
  uint2 v;
  v.x = pk2(r0.x, r1.x); v.y = pk2(r2.x, r3.x); *(uint2*)(&s[n4 + 0][k4]) = v;
  v.x = pk2(r0.y, r1.y); v.y = pk2(r2.y, r3.y); *(uint2*)(&s[n4 + 1][k4]) = v;
  v.x = pk2(r0.z, r1.z); v.y = pk2(r2.z, r3.z); *(uint2*)(&s[n4 + 2][k4]) = v;
  v.x = pk2(r0.w, r1.w); v.y = pk2(r2.w, r3.w); *(uint2*)(&s[n4 + 3][k4]) = v;
  __syncthreads();
  const int nn = t >> 3;
  const int kc = (t & 7) * 8;
#pragma unroll
  for (int i = 0; i < 2; ++i) {
    const int n = nn + i * 32;
    uint4 u = *(const uint4*)(&s[n][kc]);
    *(uint4*)(D + (size_t)(n0 + n) * K + k0 + kc) = u;
  }
}

// ---------------- kernel 2: routing ----------------
__global__ void route_kernel(const float* __restrict__ aff, const int* __restrict__ idx,
                             int* counts, int* ltok, float* lw, int* pos) {
  int t = blockIdx.x * 256 + threadIdx.x;
  if (t >= kT) return;
  int e0 = idx[t * 2 + 0];
  int e1 = idx[t * 2 + 1];
  float a0 = aff[t * kE + e0];
  float a1 = aff[t * kE + e1];
  if (e0 == e1) {
    float w = a0 / fmaxf(fabsf(a0), 1e-12f);
    int s = atomicAdd(&counts[e0], 1);
    ltok[e0 * kCap + s] = t;
    lw[e0 * kCap + s]   = w;
    pos[t * 2 + 0] = (e0 << 12) | s;
    pos[t * 2 + 1] = -1;
  } else {
    float d = fmaxf(fabsf(a0) + fabsf(a1), 1e-12f);
    int s0 = atomicAdd(&counts[e0], 1);
    ltok[e0 * kCap + s0] = t;
    lw[e0 * kCap + s0]   = a0 / d;
    int s1 = atomicAdd(&counts[e1], 1);
    ltok[e1 * kCap + s1] = t;
    lw[e1 * kCap + s1]   = a1 / d;
    pos[t * 2 + 0] = (e0 << 12) | s0;
    pos[t * 2 + 1] = (e1 << 12) | s1;
  }
}

// 256-aligned prefix offsets
__global__ void prefix_kernel(const int* __restrict__ counts, int* offs) {
  if (threadIdx.x == 0 && blockIdx.x == 0) {
    int acc = 0;
    for (int e = 0; e < kE; ++e) { offs[e] = acc; acc += (counts[e] + 255) & ~255; }
  }
}

// per-slot-row affinity weight (0 for align-pad rows)
__global__ void wrow_kernel(const int* __restrict__ counts, const int* __restrict__ offs,
                            const float* __restrict__ lw, float* __restrict__ wrow) {
  int idx = blockIdx.x * 256 + threadIdx.x;
  int e = idx >> 12, s = idx & 4095;
  int cnt = counts[e];
  int al  = (cnt + 255) & ~255;
  if (s < al) wrow[offs[e] + s] = (s < cnt) ? lw[e * kCap + s] : 0.f;
}

// wd transpose path run by gu-dispatch blocks x>=32 (fused mode).
__device__ __forceinline__ void wd_path(const float* __restrict__ wd,
                                        unsigned short* __restrict__ wdT,
                                        int xp, int y, int z, int tid, char* ldsraw) {
  const int q  = xp + 64 * y;            // [0, 1024)
  const int kt = q & 63, np = q >> 6;
  const int K = kI, N = kH;
  const float* S = wd + (size_t)z * K * N;
  unsigned short* D = wdT + (size_t)z * K * N;
  const int sub = tid >> 8, t = tid & 255;
  const int k0 = kt * 64, n0 = np * 128 + sub * 64;
  unsigned short (*s)[72] = (unsigned short(*)[72])(ldsraw + sub * 9216);
  const int n4 = (t & 15) * 4;
  const int k4 = (t >> 4) * 4;
  const float* p0 = S + (size_t)(k0 + k4) * N + n0 + n4;
  float4 r0 = *(const float4*)(p0);
  float4 r1 = *(const float4*)(p0 + N);
  float4 r2 = *(const float4*)(p0 + 2 * (size_t)N);
  float4 r3 = *(const float4*)(p0 + 3 * (size_t)N);
  uint2 v;
  v.x = pk2(r0.x, r1.x); v.y = pk2(r2.x, r3.x); *(uint2*)(&s[n4 + 0][k4]) = v;
  v.x = pk2(r0.y, r1.y); v.y = pk2(r2.y, r3.y); *(uint2*)(&s[n4 + 1][k4]) = v;
  v.x = pk2(r0.z, r1.z); v.y = pk2(r2.z, r3.z); *(uint2*)(&s[n4 + 2][k4]) = v;
  v.x = pk2(r0.w, r1.w); v.y = pk2(r2.w, r3.w); *(uint2*)(&s[n4 + 3][k4]) = v;
  __syncthreads();
  const int nn = t >> 3;
  const int kc = (t & 7) * 8;
#pragma unroll
  for (int i = 0; i < 2; ++i) {
    const int n = nn + i * 32;
    uint4 u = *(const uint4*)(&s[n][kc]);
    *(uint4*)(D + (size_t)(n0 + n) * K + k0 + kc) = u;
  }
}

// ---------------- kernel 3: fused gate+up GEMM, 8-phase (round-12) -----------
__global__ __launch_bounds__(512, 2)
void gemm_gu_kernel(const unsigned short* __restrict__ hsb,
                    const unsigned short* __restrict__ wgT,
                    const unsigned short* __restrict__ wuT,
                    const int* __restrict__ counts, const int* __restrict__ offs,
                    const int* __restrict__ ltok, const float* __restrict__ wrow,
                    unsigned short* __restrict__ hbuf,
                    const float* __restrict__ wdSrc,
                    unsigned short* __restrict__ wdDst) {
  constexpr int NT = kH / 64;
  __shared__ __attribute__((aligned(16))) unsigned short lds[2 * 32768];

  if (blockIdx.x >= 32) {
    wd_path(wdSrc, wdDst, blockIdx.x - 32, blockIdx.y, blockIdx.z,
            threadIdx.x, (char*)lds);
    return;
  }

  const int e   = blockIdx.z;
  const int cnt = counts[e];
  const int m0  = blockIdx.y * 256;
  if (m0 >= cnt) return;
  const int n0   = blockIdx.x * 128;
  const int tid  = threadIdx.x;
  const int lane = tid & 63;
  const int wv   = tid >> 6;
  const int wm   = wv >> 2;
  const int wn   = wv & 3;
  const int baseRow = offs[e] + m0;

  const int skof = ((tid & 7) ^ ((tid >> 3) & 7)) * 8;
  const int r_   = tid >> 3;
  int s0 = m0 + r_;        s0 = s0 < cnt ? s0 : cnt - 1;
  int s1 = m0 + 64 + r_;   s1 = s1 < cnt ? s1 : cnt - 1;
  int s2 = m0 + 128 + r_;  s2 = s2 < cnt ? s2 : cnt - 1;
  int s3 = m0 + 192 + r_;  s3 = s3 < cnt ? s3 : cnt - 1;
  const unsigned short* aP0 = hsb + (size_t)ltok[e * kCap + s0] * kH + skof;
  const unsigned short* aP1 = hsb + (size_t)ltok[e * kCap + s1] * kH + skof;
  const unsigned short* aP2 = hsb + (size_t)ltok[e * kCap + s2] * kH + skof;
  const unsigned short* aP3 = hsb + (size_t)ltok[e * kCap + s3] * kH + skof;
  const unsigned short* wgP0 = wgT + (size_t)e * kI * kH + (size_t)(n0 + r_) * kH + skof;
  const unsigned short* wgP1 = wgT + (size_t)e * kI * kH + (size_t)(n0 + 64 + r_) * kH + skof;
  const unsigned short* wuP0 = wuT + (size_t)e * kI * kH + (size_t)(n0 + r_) * kH + skof;
  const unsigned short* wuP1 = wuT + (size_t)e * kI * kH + (size_t)(n0 + 64 + r_) * kH + skof;

  char* ldsb = (char*)lds;
  const int stO0 = tid * 16;
  const int stO1 = tid * 16 + 8192;
  const int ar  = lane & 15;
  const int lg  = lane >> 4;
  const int sk0 = ((lg ^ (lane & 7)) << 4);
  const int sk1 = (((4 + lg) ^ (lane & 7)) << 4);

  f32x4 accG[8][2] = {};
  f32x4 accU[8][2] = {};
  bf16x8 a0[4][2], a1[4][2], wgf[2][2], wuf[2][2];

#define STG2(dst, p0, p1, tt) {                                   \
    async_copy16((dst) + stO0, (p0) + (size_t)(tt) * 64);         \
    async_copy16((dst) + stO1, (p1) + (size_t)(tt) * 64); }
#define RD_A(dst, base, mh) _Pragma("unroll")                                  \
  for (int mf = 0; mf < 4; ++mf) {                                             \
    const char* rp_ = (base) + ((mh) * 128 + wm * 64 + mf * 16 + ar) * 128;    \
    dst[mf][0] = *(const bf16x8*)(rp_ + sk0);                                  \
    dst[mf][1] = *(const bf16x8*)(rp_ + sk1); }
#define RD_W(dst, base) _Pragma("unroll")                                      \
  for (int nf = 0; nf < 2; ++nf) {                                             \
    const char* rp_ = (base) + (wn * 32 + nf * 16 + ar) * 128;                 \
    dst[nf][0] = *(const bf16x8*)(rp_ + sk0);                                  \
    dst[nf][1] = *(const bf16x8*)(rp_ + sk1); }
#define MMA16(ACC, W, A, MH)                                                   \
  __builtin_amdgcn_s_setprio(1);                                               \
  _Pragma("unroll") for (int mf = 0; mf < 4; ++mf)                             \
    _Pragma("unroll") for (int nf = 0; nf < 2; ++nf) {                         \
      ACC[(MH)*4+mf][nf] = MFMA_BF16(W[nf][0], A[mf][0], ACC[(MH)*4+mf][nf], 0, 0, 0); \
      ACC[(MH)*4+mf][nf] = MFMA_BF16(W[nf][1], A[mf][1], ACC[(MH)*4+mf][nf], 0, 0, 0); \
    }                                                                          \
  __builtin_amdgcn_s_setprio(0);

#define GU_TILE(t, SA1, SM, VM)                                                \
  {                                                                            \
    char* bc = ldsb + ((t) & 1) * 65536;                                       \
    char* bo = ldsb + (((t) + 1) & 1) * 65536;                                 \
    RD_A(a0, bc, 0); RD_W(wgf, bc + 32768);                                    \
    if (SA1) STG2(bo + 16384, aP2, aP3, (t) + 1);                              \
    __builtin_amdgcn_s_barrier();                                              \
    MMA16(accG, wgf, a0, 0);                                                   \
    __builtin_amdgcn_s_barrier();                                              \
    RD_W(wuf, bc + 49152);                                                     \
    if (SM) STG2(bc, aP0, aP1, (t) + 2);                                       \
    __builtin_amdgcn_s_barrier();                                              \
    MMA16(accU, wuf, a0, 0);                                                   \
    __builtin_amdgcn_s_barrier();                                              \
    RD_A(a1, bc, 1);                                                           \
    if (SM) STG2(bc + 32768, wgP0, wgP1, (t) + 2);                             \
    __builtin_amdgcn_s_barrier();                                              \
    MMA16(accG, wgf, a1, 1);                                                   \
    __builtin_amdgcn_s_barrier();                                              \
    if (SM) STG2(bc + 49152, wuP0, wuP1, (t) + 2);                             \
    __builtin_amdgcn_s_barrier();                                              \
    MMA16(accU, wuf, a1, 1);                                                   \
    if ((VM) >= 0) {                                                           \
      asm volatile("s_waitcnt vmcnt(%0)" :: "i"((VM) < 0 ? 0 : (VM)) : "memory"); \
      __builtin_amdgcn_s_barrier();                                            \
    }                                                                          \
  }

  {
    char* b0 = ldsb;
    char* b1 = ldsb + 65536;
    STG2(b0,         aP0, aP1, 0);
    STG2(b0 + 16384, aP2, aP3, 0);
    STG2(b0 + 32768, wgP0, wgP1, 0);
    STG2(b0 + 49152, wuP0, wuP1, 0);
    STG2(b1,         aP0, aP1, 1);
    STG2(b1 + 32768, wgP0, wgP1, 1);
    STG2(b1 + 49152, wuP0, wuP1, 1);
    asm volatile("s_waitcnt vmcnt(6)" ::: "memory");
    __builtin_amdgcn_s_barrier();
  }

  for (int t = 0; t < NT - 2; ++t) GU_TILE(t, 1, 1, 6);
  GU_TILE(NT - 2, 1, 0, 0);
  GU_TILE(NT - 1, 0, 0, -1);
#undef GU_TILE

  const int lr4 = lg * 4;
#pragma unroll
  for (int mh = 0; mh < 2; ++mh)
#pragma unroll
    for (int mf = 0; mf < 4; ++mf) {
      const int grow = baseRow + mh * 128 + wm * 64 + mf * 16 + ar;
      const float wf = wrow[grow];
#pragma unroll
      for (int nf = 0; nf < 2; ++nf) {
        const int n = n0 + wn * 32 + nf * 16 + lr4;
        f32x4 g = accG[mh * 4 + mf][nf], u = accU[mh * 4 + mf][nf];
        float h0 = silu_f(g[0]) * u[0] * wf;
        float h1 = silu_f(g[1]) * u[1] * wf;
        float h2 = silu_f(g[2]) * u[2] * wf;
        float h3 = silu_f(g[3]) * u[3] * wf;
        uint2 v;
        v.x = pk2(h0, h1);
        v.y = pk2(h2, h3);
        *(uint2*)(hbuf + ((size_t)grow * kI + n)) = v;
      }
    }
#undef STG2
#undef RD_A
#undef RD_W
#undef MMA16
}

// ---------------- kernel 4: down GEMM, BM=128, BN=128, 2 blocks/CU -----------
// 8 waves (2m x 4n): per-wave 64m x 32n -> acc[4][2] (32 regs).
// LDS per buffer (32 KiB): A [128][64] @0, W [128][64] @16384. dbuf = 64 KiB.
// Tile: ph1 { rdA(mf01), rdW | BAR | MMA8 | BAR }
//       ph2 { rdA(mf23) | BAR | MMA8 }
//       tail { stage A,W(t+2)->bc ; vmcnt(4) ; BAR }   (bc reads all done: BAR'd)
// grid (kH/128=16, kCap/128=32, E), 512 threads.
__global__ __launch_bounds__(512, 4)
void gemm_dn_kernel(const unsigned short* __restrict__ hbuf,
                    const unsigned short* __restrict__ wdT,   // (E, H, I) bf16
                    const int* __restrict__ counts, const int* __restrict__ offs,
                    float* __restrict__ obuf) {
  constexpr int NT = kI / 64;   // 64 K-tiles
  __shared__ __attribute__((aligned(16))) unsigned short lds[2 * 16384];

  const int e   = blockIdx.z;
  const int cnt = counts[e];
  const int m0  = blockIdx.y * 128;
  if (m0 >= cnt) return;
  const int n0   = blockIdx.x * 128;
  const int tid  = threadIdx.x;
  const int lane = tid & 63;
  const int wv   = tid >> 6;
  const int wm   = wv >> 2;       // 2 m-halves of 64
  const int wn   = wv & 3;        // 4 n-panels of 32
  const int baseRow = offs[e] + m0;

  const int skof = ((tid & 7) ^ ((tid >> 3) & 7)) * 8;
  const int r_   = tid >> 3;
  const unsigned short* aP0 = hbuf + (size_t)(baseRow + r_) * kI + skof;
  const unsigned short* aP1 = hbuf + (size_t)(baseRow + 64 + r_) * kI + skof;
  const unsigned short* wB = wdT + (size_t)e * kH * kI;
  const unsigned short* wP0 = wB + (size_t)(n0 + r_) * kI + skof;
  const unsigned short* wP1 = wB + (size_t)(n0 + 64 + r_) * kI + skof;

  char* ldsb = (char*)lds;
  const int stO0 = tid * 16;
  const int stO1 = tid * 16 + 8192;
  const int ar  = lane & 15;
  const int lg  = lane >> 4;
  const int sk0 = ((lg ^ (lane & 7)) << 4);
  const int sk1 = (((4 + lg) ^ (lane & 7)) << 4);

  f32x4 acc[4][2] = {};
  bf16x8 a0[2][2], a1[2][2], w0[2][2];

#define STG2(dst, p0, p1, tt) {                                   \
    async_copy16((dst) + stO0, (p0) + (size_t)(tt) * 64);         \
    async_copy16((dst) + stO1, (p1) + (size_t)(tt) * 64); }
#define RD_A2(dst, base, mp) _Pragma("unroll")                                 \
  for (int mf = 0; mf < 2; ++mf) {                                             \
    const char* rp_ = (base) + (wm * 64 + ((mp) * 2 + mf) * 16 + ar) * 128;    \
    dst[mf][0] = *(const bf16x8*)(rp_ + sk0);                                  \
    dst[mf][1] = *(const bf16x8*)(rp_ + sk1); }
#define RD_W(dst, base) _Pragma("unroll")                                      \
  for (int nf = 0; nf < 2; ++nf) {                                             \
    const char* rp_ = (base) + 16384 + (wn * 32 + nf * 16 + ar) * 128;         \
    dst[nf][0] = *(const bf16x8*)(rp_ + sk0);                                  \
    dst[nf][1] = *(const bf16x8*)(rp_ + sk1); }
#define MMA8(A, MP)                                                            \
  __builtin_amdgcn_s_setprio(1);                                               \
  _Pragma("unroll") for (int mf = 0; mf < 2; ++mf)                             \
    _Pragma("unroll") for (int nf = 0; nf < 2; ++nf) {                         \
      acc[(MP)*2+mf][nf] = MFMA_BF16(w0[nf][0], A[mf][0], acc[(MP)*2+mf][nf], 0, 0, 0); \
      acc[(MP)*2+mf][nf] = MFMA_BF16(w0[nf][1], A[mf][1], acc[(MP)*2+mf][nf], 0, 0, 0); \
    }                                                                          \
  __builtin_amdgcn_s_setprio(0);

#define DN_TILE(t, SM, VM)                                                     \
  {                                                                            \
    char* bc = ldsb + ((t) & 1) * 32768;                                       \
    RD_A2(a0, bc, 0); RD_W(w0, bc);                                            \
    __builtin_amdgcn_s_barrier();                                              \
    MMA8(a0, 0);                                                               \
    __builtin_amdgcn_s_barrier();                                              \
    RD_A2(a1, bc, 1);                                                          \
    __builtin_amdgcn_s_barrier();                                              \
    MMA8(a1, 1);                                                               \
    if (SM) { STG2(bc, aP0, aP1, (t) + 2);                                     \
              STG2(bc + 16384, wP0, wP1, (t) + 2); }                           \
    if ((VM) >= 0) {                                                           \
      asm volatile("s_waitcnt vmcnt(%0)" :: "i"((VM) < 0 ? 0 : (VM)) : "memory"); \
      __builtin_amdgcn_s_barrier();                                            \
    }                                                                          \
  }

  {
    char* b0 = ldsb;
    char* b1 = ldsb + 32768;
    STG2(b0,         aP0, aP1, 0);
    STG2(b0 + 16384, wP0, wP1, 0);
    STG2(b1,         aP0, aP1, 1);
    STG2(b1 + 16384, wP0, wP1, 1);
    asm volatile("s_waitcnt vmcnt(4)" ::: "memory");
    __builtin_amdgcn_s_barrier();
  }

  for (int t = 0; t < NT - 2; ++t) DN_TILE(t, 1, 4);
  DN_TILE(NT - 2, 0, 0);
  DN_TILE(NT - 1, 0, -1);
#undef DN_TILE

  const int lr4 = lg * 4;
#pragma unroll
  for (int mf = 0; mf < 4; ++mf) {
    const int grow = baseRow + wm * 64 + mf * 16 + ar;
#pragma unroll
    for (int nf = 0; nf < 2; ++nf) {
      const int n = n0 + wn * 32 + nf * 16 + lr4;
      *(f32x4*)(obuf + (size_t)grow * kH + n) = acc[mf][nf];
    }
  }
#undef STG2
#undef RD_A2
#undef RD_W
#undef MMA8
}

// ---------------- kernel 5: combine obuf slots -> out ----------------
__global__ void combine_kernel(const float* __restrict__ obuf,
                               const int* __restrict__ pos,
                               const int* __restrict__ offs,
                               float* __restrict__ out) {
  const int t   = blockIdx.y;
  const int col = blockIdx.x * 1024 + threadIdx.x * 4;
  const int c0  = pos[t * 2 + 0];
  const int c1  = pos[t * 2 + 1];
  const int row0 = offs[c0 >> 12] + (c0 & 4095);
  float4 v = *(const float4*)(obuf + (size_t)row0 * kH + col);
  if (c1 >= 0) {
    const int row1 = offs[c1 >> 12] + (c1 & 4095);
    float4 w = *(const float4*)(obuf + (size_t)row1 * kH + col);
    v.x += w.x; v.y += w.y; v.z += w.z; v.w += w.w;
  }
  *(float4*)(out + (size_t)t * kH + col) = v;
}

// ---------------- launcher ----------------
extern "C" void kernel_launch(void* const* d_in, const int* in_sizes, int n_in,
                              void* d_out, int out_size, void* d_ws, size_t ws_size,
                              hipStream_t stream) {
  const float* hs   = (const float*)d_in[0];
  const float* aff  = (const float*)d_in[1];
  const int*   eidx = (const int*)d_in[2];
  const float* wg   = (const float*)d_in[3];
  const float* wu   = (const float*)d_in[4];
  const float* wd   = (const float*)d_in[5];
  float* out = (float*)d_out;

  char* ws = (char*)d_ws;
  unsigned short* hsb  = (unsigned short*)(ws + HSB_OFF);
  unsigned short* hbuf = (unsigned short*)(ws + HBUF_OFF);
  unsigned short* wgT  = (unsigned short*)(ws + RA_OFF);
  unsigned short* wuT  = (unsigned short*)(ws + RB_OFF);
  int*            cnts = (int*)(ws + CNT_OFF);
  int*            offs = (int*)(ws + OFF_OFF);
  int*            ltok = (int*)(ws + LTOK_OFF);
  float*          lwgt = (float*)(ws + LW_OFF);
  int*            pos  = (int*)(ws + POS_OFF);
  float*          wrow = (float*)(ws + WROW_OFF);

  const bool fused = (ws_size >= WS_NEED);
  unsigned short* wdT  = fused ? (unsigned short*)(ws + WD_OFF)
                               : (unsigned short*)(ws + RA_OFF);
  float*          obuf = fused ? (float*)(ws + RA_OFF)
                               : (float*)(ws + RB_OFF);

  hipMemsetAsync(cnts, 0, kE * sizeof(int), stream);

  cvt_hs_kernel<<<(kT * kH) / (256 * 8), 256, 0, stream>>>(hs, hsb);
  route_kernel<<<kT / 256, 256, 0, stream>>>(aff, eidx, cnts, ltok, lwgt, pos);
  prefix_kernel<<<1, 64, 0, stream>>>(cnts, offs);
  wrow_kernel<<<(kE * kCap) / 256, 256, 0, stream>>>(cnts, offs, lwgt, wrow);

  tcvt_kernel<<<dim3(kI / 64, kH / 64, kE), 256, 0, stream>>>(wg, wgT, kH, kI);
  tcvt_kernel<<<dim3(kI / 64, kH / 64, kE), 256, 0, stream>>>(wu, wuT, kH, kI);

  if (fused) {
    gemm_gu_kernel<<<dim3(96, kCap / 256, kE), 512, 0, stream>>>(
        hsb, wgT, wuT, cnts, offs, ltok, wrow, hbuf, wd, wdT);
  } else {
    gemm_gu_kernel<<<dim3(32, kCap / 256, kE), 512, 0, stream>>>(
        hsb, wgT, wuT, cnts, offs, ltok, wrow, hbuf, nullptr, nullptr);
    tcvt_kernel<<<dim3(kH / 64, kI / 64, kE), 256, 0, stream>>>(wd, wdT, kI, kH);
  }

  gemm_dn_kernel<<<dim3(kH / 128, kCap / 128, kE), 512, 0, stream>>>(
      hbuf, wdT, cnts, offs, obuf);

  combine_kernel<<<dim3(kH / 1024, kT), 256, 0, stream>>>(obuf, pos, offs, out);
}